// Round 1
// baseline (1065.410 us; speedup 1.0000x reference)
//
#include <hip/hip_runtime.h>
#include <hip/hip_bf16.h>
#include <math.h>

#define LN_EPS 1e-5f

typedef short short8 __attribute__((ext_vector_type(8)));
typedef float floatx4 __attribute__((ext_vector_type(4)));

__device__ inline unsigned short f2bf(float f) {
    unsigned int u = __float_as_uint(f);
    u += 0x7fff + ((u >> 16) & 1);   // round-to-nearest-even
    return (unsigned short)(u >> 16);
}

// ---------------------------------------------------------------------------
// Generic 128x128-tile bf16 MFMA GEMM.
//  A: MxK row-major (fp32, or bf16 when A_BF16)
//  B: B_TRANS ? NxK row-major (i.e. B^T given) : KxN row-major
//  C: MxN
//  EPI: 0 = store fp32; 1 = +bias, store fp32; 2 = +bias, exact GELU, store bf16
// M,N multiples of 128; K multiple of 32 (true for all uses here).
// ---------------------------------------------------------------------------
template<int A_BF16, int B_TRANS, int EPI>
__global__ __launch_bounds__(256) void gemm_kernel(
    const void* __restrict__ Aptr, const void* __restrict__ Bptr,
    const float* __restrict__ bias, void* __restrict__ Cptr,
    int M, int N, int K, long sA, long sB, long sC)
{
    __shared__ unsigned short lds_a[128][40];   // pad 32->40: keeps 16B align (80B rows)
    __shared__ unsigned short lds_b[128][40];   // lds_b[n][k]

    const int tid  = threadIdx.x;
    const int lane = tid & 63;
    const int wave = tid >> 6;
    const int quad = lane >> 4;
    const int l16  = lane & 15;
    const int wm = wave >> 1, wn = wave & 1;
    const int tile_m = blockIdx.y * 128;
    const int tile_n = blockIdx.x * 128;
    const int batch  = blockIdx.z;

    const float*          Af = (const float*)Aptr          + (size_t)batch * sA;
    const unsigned short* Ah = (const unsigned short*)Aptr + (size_t)batch * sA;
    const float*          Bf = (const float*)Bptr          + (size_t)batch * sB;

    floatx4 acc[4][4];
    const floatx4 zero = {0.f, 0.f, 0.f, 0.f};
#pragma unroll
    for (int i = 0; i < 4; i++)
#pragma unroll
        for (int j = 0; j < 4; j++) acc[i][j] = zero;

    for (int k0 = 0; k0 < K; k0 += 32) {
        // ---- stage A tile (128x32) into lds_a[m][k] as bf16 ----
        if (A_BF16) {
#pragma unroll
            for (int i = 0; i < 2; i++) {
                int f = tid + i * 256;              // 512 chunks of 8 elems
                int row = f >> 2, c8 = (f & 3) * 8;
                const unsigned short* src = Ah + (size_t)(tile_m + row) * K + k0 + c8;
                uint4 v = *(const uint4*)src;
                *(uint4*)&lds_a[row][c8] = v;
            }
        } else {
#pragma unroll
            for (int i = 0; i < 4; i++) {
                int f = tid + i * 256;              // 1024 chunks of 4 elems
                int row = f >> 3, c4 = (f & 7) * 4;
                const float* src = Af + (size_t)(tile_m + row) * K + k0 + c4;
                float4 v = *(const float4*)src;
                ushort4 h;
                h.x = f2bf(v.x); h.y = f2bf(v.y); h.z = f2bf(v.z); h.w = f2bf(v.w);
                *(ushort4*)&lds_a[row][c4] = h;
            }
        }
        // ---- stage B tile into lds_b[n][k] as bf16 ----
        if (B_TRANS) {
#pragma unroll
            for (int i = 0; i < 4; i++) {
                int f = tid + i * 256;
                int row = f >> 3, c4 = (f & 7) * 4;   // row = n, c4 = k
                const float* src = Bf + (size_t)(tile_n + row) * K + k0 + c4;
                float4 v = *(const float4*)src;
                ushort4 h;
                h.x = f2bf(v.x); h.y = f2bf(v.y); h.z = f2bf(v.z); h.w = f2bf(v.w);
                *(ushort4*)&lds_b[row][c4] = h;
            }
        } else {
#pragma unroll
            for (int i = 0; i < 4; i++) {
                int f = tid + i * 256;                // 32 k-rows x 32 float4s
                int kr = f >> 5, c4 = (f & 31) * 4;   // kr = k, c4 = n
                const float* src = Bf + (size_t)(k0 + kr) * N + tile_n + c4;
                float4 v = *(const float4*)src;
                lds_b[c4 + 0][kr] = f2bf(v.x);
                lds_b[c4 + 1][kr] = f2bf(v.y);
                lds_b[c4 + 2][kr] = f2bf(v.z);
                lds_b[c4 + 3][kr] = f2bf(v.w);
            }
        }
        __syncthreads();

        short8 afr[4], bfr[4];
#pragma unroll
        for (int i = 0; i < 4; i++)
            afr[i] = *(const short8*)&lds_a[wm * 64 + i * 16 + l16][quad * 8];
#pragma unroll
        for (int j = 0; j < 4; j++)
            bfr[j] = *(const short8*)&lds_b[wn * 64 + j * 16 + l16][quad * 8];
#pragma unroll
        for (int i = 0; i < 4; i++)
#pragma unroll
            for (int j = 0; j < 4; j++)
                acc[i][j] = __builtin_amdgcn_mfma_f32_16x16x32_bf16(
                    afr[i], bfr[j], acc[i][j], 0, 0, 0);
        __syncthreads();
    }

    // ---- epilogue ----
#pragma unroll
    for (int i = 0; i < 4; i++) {
#pragma unroll
        for (int j = 0; j < 4; j++) {
            int col = tile_n + wn * 64 + j * 16 + l16;
            float bv = (EPI >= 1) ? bias[col] : 0.f;
#pragma unroll
            for (int r = 0; r < 4; r++) {
                int row = tile_m + wm * 64 + i * 16 + quad * 4 + r;
                float v = acc[i][j][r] + bv;
                if (EPI == 2) {
                    v = 0.5f * v * (1.0f + erff(v * 0.70710678118654752f));
                    unsigned short* C = (unsigned short*)Cptr + (size_t)batch * sC;
                    C[(size_t)row * N + col] = f2bf(v);
                } else {
                    float* C = (float*)Cptr + (size_t)batch * sC;
                    C[(size_t)row * N + col] = v;
                }
            }
        }
    }
}

// ---------------------------------------------------------------------------
// Row softmax over S=2048 with scale + additive mask, in place. 1 block/row.
// ---------------------------------------------------------------------------
__global__ __launch_bounds__(256) void softmax_kernel(
    float* __restrict__ scores, const float* __restrict__ mask, int S, float scale)
{
    __shared__ float red[4];
    const int row = blockIdx.x;
    const int b   = row / S;
    float* p        = scores + (size_t)row * S;
    const float* mk = mask + (size_t)b * S;
    const int tid  = threadIdx.x;
    const int lane = tid & 63;
    const int wav  = tid >> 6;

    float4 v0 = *(const float4*)(p + tid * 4);
    float4 v1 = *(const float4*)(p + 1024 + tid * 4);
    float4 m0 = *(const float4*)(mk + tid * 4);
    float4 m1 = *(const float4*)(mk + 1024 + tid * 4);
    v0.x = v0.x * scale + m0.x;  v0.y = v0.y * scale + m0.y;
    v0.z = v0.z * scale + m0.z;  v0.w = v0.w * scale + m0.w;
    v1.x = v1.x * scale + m1.x;  v1.y = v1.y * scale + m1.y;
    v1.z = v1.z * scale + m1.z;  v1.w = v1.w * scale + m1.w;

    float mx = fmaxf(fmaxf(fmaxf(v0.x, v0.y), fmaxf(v0.z, v0.w)),
                     fmaxf(fmaxf(v1.x, v1.y), fmaxf(v1.z, v1.w)));
#pragma unroll
    for (int off = 32; off > 0; off >>= 1) mx = fmaxf(mx, __shfl_down(mx, off));
    if (lane == 0) red[wav] = mx;
    __syncthreads();
    mx = fmaxf(fmaxf(red[0], red[1]), fmaxf(red[2], red[3]));
    __syncthreads();

    v0.x = __expf(v0.x - mx); v0.y = __expf(v0.y - mx);
    v0.z = __expf(v0.z - mx); v0.w = __expf(v0.w - mx);
    v1.x = __expf(v1.x - mx); v1.y = __expf(v1.y - mx);
    v1.z = __expf(v1.z - mx); v1.w = __expf(v1.w - mx);

    float s = v0.x + v0.y + v0.z + v0.w + v1.x + v1.y + v1.z + v1.w;
#pragma unroll
    for (int off = 32; off > 0; off >>= 1) s += __shfl_down(s, off);
    if (lane == 0) red[wav] = s;
    __syncthreads();
    s = red[0] + red[1] + red[2] + red[3];
    float inv = 1.0f / s;

    v0.x *= inv; v0.y *= inv; v0.z *= inv; v0.w *= inv;
    v1.x *= inv; v1.y *= inv; v1.z *= inv; v1.w *= inv;
    *(float4*)(p + tid * 4)        = v0;
    *(float4*)(p + 1024 + tid * 4) = v1;
}

// ---------------------------------------------------------------------------
// out_row = LayerNorm(x_row + y_row) * g + b.  D = 1024, 1 block/row.
// Safe when out == y (in-place).
// ---------------------------------------------------------------------------
__global__ __launch_bounds__(256) void add_ln_kernel(
    const float* __restrict__ X, const float* __restrict__ Y,
    const float* __restrict__ g, const float* __restrict__ bta,
    float* __restrict__ out, int D)
{
    __shared__ float red[8];
    const int row = blockIdx.x;
    const float* x = X + (size_t)row * D;
    const float* y = Y + (size_t)row * D;
    float* o       = out + (size_t)row * D;
    const int tid  = threadIdx.x;
    const int lane = tid & 63;
    const int wav  = tid >> 6;

    float4 a  = *(const float4*)(x + tid * 4);
    float4 b4 = *(const float4*)(y + tid * 4);
    float v0 = a.x + b4.x, v1 = a.y + b4.y, v2 = a.z + b4.z, v3 = a.w + b4.w;

    float s1 = v0 + v1 + v2 + v3;
    float s2 = v0 * v0 + v1 * v1 + v2 * v2 + v3 * v3;
#pragma unroll
    for (int off = 32; off > 0; off >>= 1) {
        s1 += __shfl_down(s1, off);
        s2 += __shfl_down(s2, off);
    }
    if (lane == 0) { red[wav] = s1; red[4 + wav] = s2; }
    __syncthreads();
    s1 = red[0] + red[1] + red[2] + red[3];
    s2 = red[4] + red[5] + red[6] + red[7];
    const float mu  = s1 / (float)D;
    const float var = s2 / (float)D - mu * mu;
    const float rs  = rsqrtf(var + LN_EPS);

    float4 gg = *(const float4*)(g + tid * 4);
    float4 bb = *(const float4*)(bta + tid * 4);
    float4 r;
    r.x = (v0 - mu) * rs * gg.x + bb.x;
    r.y = (v1 - mu) * rs * gg.y + bb.y;
    r.z = (v2 - mu) * rs * gg.z + bb.z;
    r.w = (v3 - mu) * rs * gg.w + bb.w;
    *(float4*)(o + tid * 4) = r;
}

// ---------------------------------------------------------------------------
extern "C" void kernel_launch(void* const* d_in, const int* in_sizes, int n_in,
                              void* d_out, int out_size, void* d_ws, size_t ws_size,
                              hipStream_t stream) {
    (void)in_sizes; (void)n_in; (void)out_size; (void)ws_size;
    const float* x    = (const float*)d_in[0];
    const float* mask = (const float*)d_in[1];
    const float* w1   = (const float*)d_in[2];
    const float* b1   = (const float*)d_in[3];
    const float* w2   = (const float*)d_in[4];
    const float* b2   = (const float*)d_in[5];
    const float* ln1g = (const float*)d_in[6];
    const float* ln1b = (const float*)d_in[7];
    const float* ln2g = (const float*)d_in[8];
    const float* ln2b = (const float*)d_in[9];
    float* out = (float*)d_out;

    const int B = 4, S = 2048, D = 1024, DFF = 4096;

    char* ws = (char*)d_ws;
    float* scores = (float*)ws;                                        // B*S*S fp32 (64MB)
    float* hbuf   = (float*)(ws + (size_t)B * S * S * 4);              // B*S*D fp32 (32MB)
    float* ffn    = (float*)(ws + (size_t)B * S * S * 4
                                + (size_t)B * S * D * 4);              // B*S*D fp32 (32MB)
    unsigned short* act = (unsigned short*)ws;                         // reuse: B*S*DFF bf16

    // 1. scores[b] = x[b] @ x[b]^T            (M=N=S, K=D)
    hipLaunchKernelGGL((gemm_kernel<0, 1, 0>), dim3(S / 128, S / 128, B), dim3(256), 0, stream,
                       (const void*)x, (const void*)x, (const float*)nullptr, (void*)scores,
                       S, S, D, (long)S * D, (long)S * D, (long)S * S);
    // 2. softmax rows (scale 1/sqrt(D) + mask)
    softmax_kernel<<<B * S, 256, 0, stream>>>(scores, mask, S, 0.03125f);
    // 3. attn[b] = probs[b] @ x[b]            (M=S, N=D, K=S)
    hipLaunchKernelGGL((gemm_kernel<0, 0, 0>), dim3(D / 128, S / 128, B), dim3(256), 0, stream,
                       (const void*)scores, (const void*)x, (const float*)nullptr, (void*)hbuf,
                       S, D, S, (long)S * S, (long)S * D, (long)S * D);
    // 4. h = LN(x + attn)   (in place into hbuf)
    add_ln_kernel<<<B * S, 256, 0, stream>>>(x, hbuf, ln1g, ln1b, hbuf, D);
    // 5. act = gelu(h @ w1 + b1)  -> bf16     (M=B*S, N=DFF, K=D)
    hipLaunchKernelGGL((gemm_kernel<0, 0, 2>), dim3(DFF / 128, (B * S) / 128, 1), dim3(256), 0, stream,
                       (const void*)hbuf, (const void*)w1, b1, (void*)act,
                       B * S, DFF, D, 0L, 0L, 0L);
    // 6. ffn = act @ w2 + b2                  (M=B*S, N=D, K=DFF)
    hipLaunchKernelGGL((gemm_kernel<1, 0, 1>), dim3(D / 128, (B * S) / 128, 1), dim3(256), 0, stream,
                       (const void*)act, (const void*)w2, b2, (void*)ffn,
                       B * S, D, DFF, 0L, 0L, 0L);
    // 7. out = LN(h + ffn)
    add_ln_kernel<<<B * S, 256, 0, stream>>>(hbuf, ffn, ln2g, ln2b, out, D);
}

// Round 2
// 530.924 us; speedup vs baseline: 2.0067x; 2.0067x over previous
//
#include <hip/hip_runtime.h>
#include <hip/hip_bf16.h>
#include <math.h>

#define LN_EPS 1e-5f

typedef short short8 __attribute__((ext_vector_type(8)));
typedef float floatx4 __attribute__((ext_vector_type(4)));

__device__ inline unsigned short f2bf(float f) {
    unsigned int u = __float_as_uint(f);
    u += 0x7fff + ((u >> 16) & 1);   // round-to-nearest-even
    return (unsigned short)(u >> 16);
}

__device__ inline void gl_lds16(const unsigned short* g, unsigned short* l) {
    // async global->LDS, 16 bytes per lane. LDS dest must be wave-uniform
    // base + lane*16 (it is: we pass base + lane*8 shorts).
    __builtin_amdgcn_global_load_lds(
        (__attribute__((address_space(1))) const void*)g,
        (__attribute__((address_space(3))) void*)l, 16, 0, 0);
}

// ---------------------------------------------------------------------------
// bf16 MFMA GEMM, 128x128 tile, BK=32, m97 structure.
//  A: MxK row-major bf16.   B: NxK row-major bf16 (i.e. B^T).
//  EPI: 0 = store fp32; 1 = +bias fp32; 2 = +bias, exact GELU, store bf16.
// M,N mult of 128; K mult of 32.
// ---------------------------------------------------------------------------
template<int EPI>
__global__ __launch_bounds__(256) void gemm_bt(
    const unsigned short* __restrict__ A, const unsigned short* __restrict__ B,
    const float* __restrict__ bias, void* __restrict__ Cptr,
    int M, int N, int K, long sA, long sB, long sC)
{
    __shared__ unsigned short lds_a[128 * 32];   // [m][k], unpadded (global_load_lds)
    __shared__ unsigned short lds_b[128 * 32];   // [n][k]

    const int tid  = threadIdx.x;
    const int lane = tid & 63;
    const int wave = tid >> 6;
    const int quad = lane >> 4;
    const int l16  = lane & 15;
    const int wm = wave >> 1, wn = wave & 1;
    const int tile_m = blockIdx.y * 128;
    const int tile_n = blockIdx.x * 128;
    const int batch  = blockIdx.z;

    const unsigned short* Ab = A + (size_t)batch * sA;
    const unsigned short* Bb = B + (size_t)batch * sB;

    // staging addresses: load r (r=0,1) covers rows r*64 + wave*16 + (lane>>2),
    // k-offset (lane&3)*8 shorts (16B). LDS offset = r*2048 + wave*512 + lane*8
    // shorts -> contiguous lane*16 bytes within the wave's 1KB chunk.
    const int srow = wave * 16 + (lane >> 2);
    const int scol = (lane & 3) * 8;
    const unsigned short* gA0 = Ab + (size_t)(tile_m + srow) * K + scol;
    const unsigned short* gA1 = Ab + (size_t)(tile_m + 64 + srow) * K + scol;
    const unsigned short* gB0 = Bb + (size_t)(tile_n + srow) * K + scol;
    const unsigned short* gB1 = Bb + (size_t)(tile_n + 64 + srow) * K + scol;
    unsigned short* lA0 = &lds_a[wave * 512 + lane * 8];
    unsigned short* lA1 = &lds_a[2048 + wave * 512 + lane * 8];
    unsigned short* lB0 = &lds_b[wave * 512 + lane * 8];
    unsigned short* lB1 = &lds_b[2048 + wave * 512 + lane * 8];

    floatx4 acc[4][4];
    const floatx4 zero = {0.f, 0.f, 0.f, 0.f};
#pragma unroll
    for (int i = 0; i < 4; i++)
#pragma unroll
        for (int j = 0; j < 4; j++) acc[i][j] = zero;

    for (int k0 = 0; k0 < K; k0 += 32) {
        __syncthreads();   // all waves done reading LDS from previous iter
        gl_lds16(gA0 + k0, lA0);
        gl_lds16(gA1 + k0, lA1);
        gl_lds16(gB0 + k0, lB0);
        gl_lds16(gB1 + k0, lB1);
        __syncthreads();   // compiler emits vmcnt(0) drain before barrier

        short8 afr[4], bfr[4];
#pragma unroll
        for (int i = 0; i < 4; i++)
            afr[i] = *(const short8*)&lds_a[(wm * 64 + i * 16 + l16) * 32 + quad * 8];
#pragma unroll
        for (int j = 0; j < 4; j++)
            bfr[j] = *(const short8*)&lds_b[(wn * 64 + j * 16 + l16) * 32 + quad * 8];
#pragma unroll
        for (int i = 0; i < 4; i++)
#pragma unroll
            for (int j = 0; j < 4; j++)
                acc[i][j] = __builtin_amdgcn_mfma_f32_16x16x32_bf16(
                    afr[i], bfr[j], acc[i][j], 0, 0, 0);
    }

    // ---- epilogue ----
#pragma unroll
    for (int i = 0; i < 4; i++) {
#pragma unroll
        for (int j = 0; j < 4; j++) {
            int col = tile_n + wn * 64 + j * 16 + l16;
            float bv = (EPI >= 1) ? bias[col] : 0.f;
#pragma unroll
            for (int r = 0; r < 4; r++) {
                int row = tile_m + wm * 64 + i * 16 + quad * 4 + r;
                float v = acc[i][j][r] + bv;
                if (EPI == 2) {
                    v = 0.5f * v * (1.0f + erff(v * 0.70710678118654752f));
                    unsigned short* C = (unsigned short*)Cptr + (size_t)batch * sC;
                    C[(size_t)row * N + col] = f2bf(v);
                } else {
                    float* C = (float*)Cptr + (size_t)batch * sC;
                    C[(size_t)row * N + col] = v;
                }
            }
        }
    }
}

// ---------------------------------------------------------------------------
// fp32 -> bf16 elementwise cast. n mult of 1024.
// ---------------------------------------------------------------------------
__global__ __launch_bounds__(256) void cvt_bf16_kernel(
    const float* __restrict__ in, unsigned short* __restrict__ out)
{
    size_t i = ((size_t)blockIdx.x * 256 + threadIdx.x) * 4;
    float4 v = *(const float4*)(in + i);
    ushort4 h;
    h.x = f2bf(v.x); h.y = f2bf(v.y); h.z = f2bf(v.z); h.w = f2bf(v.w);
    *(ushort4*)(out + i) = h;
}

// ---------------------------------------------------------------------------
// Batched transpose + cast: in [R,C] fp32 -> out [C,R] bf16. R,C mult of 32.
// ---------------------------------------------------------------------------
__global__ __launch_bounds__(256) void transpose_cvt_kernel(
    const float* __restrict__ in, unsigned short* __restrict__ out,
    int R, int C, long sIn, long sOut)
{
    __shared__ float tile[32][33];
    const int tc = blockIdx.x * 32, tr = blockIdx.y * 32;
    const float* src = in + (size_t)blockIdx.z * sIn;
    unsigned short* dst = out + (size_t)blockIdx.z * sOut;
    const int tx = threadIdx.x & 31, ty = threadIdx.x >> 5;
#pragma unroll
    for (int i = 0; i < 4; i++)
        tile[ty + i * 8][tx] = src[(size_t)(tr + ty + i * 8) * C + tc + tx];
    __syncthreads();
#pragma unroll
    for (int i = 0; i < 4; i++)
        dst[(size_t)(tc + ty + i * 8) * R + tr + tx] = f2bf(tile[tx][ty + i * 8]);
}

// ---------------------------------------------------------------------------
// Row softmax over S=2048 (scale + additive mask), fp32 in -> bf16 out.
// ---------------------------------------------------------------------------
__global__ __launch_bounds__(256) void softmax_kernel(
    const float* __restrict__ scores, unsigned short* __restrict__ probs,
    const float* __restrict__ mask, int S, float scale)
{
    __shared__ float red[4];
    const int row = blockIdx.x;
    const int b   = row / S;
    const float* p        = scores + (size_t)row * S;
    unsigned short* pr    = probs + (size_t)row * S;
    const float* mk = mask + (size_t)b * S;
    const int tid  = threadIdx.x;
    const int lane = tid & 63;
    const int wav  = tid >> 6;

    float4 v0 = *(const float4*)(p + tid * 4);
    float4 v1 = *(const float4*)(p + 1024 + tid * 4);
    float4 m0 = *(const float4*)(mk + tid * 4);
    float4 m1 = *(const float4*)(mk + 1024 + tid * 4);
    v0.x = v0.x * scale + m0.x;  v0.y = v0.y * scale + m0.y;
    v0.z = v0.z * scale + m0.z;  v0.w = v0.w * scale + m0.w;
    v1.x = v1.x * scale + m1.x;  v1.y = v1.y * scale + m1.y;
    v1.z = v1.z * scale + m1.z;  v1.w = v1.w * scale + m1.w;

    float mx = fmaxf(fmaxf(fmaxf(v0.x, v0.y), fmaxf(v0.z, v0.w)),
                     fmaxf(fmaxf(v1.x, v1.y), fmaxf(v1.z, v1.w)));
#pragma unroll
    for (int off = 32; off > 0; off >>= 1) mx = fmaxf(mx, __shfl_down(mx, off));
    if (lane == 0) red[wav] = mx;
    __syncthreads();
    mx = fmaxf(fmaxf(red[0], red[1]), fmaxf(red[2], red[3]));
    __syncthreads();

    v0.x = __expf(v0.x - mx); v0.y = __expf(v0.y - mx);
    v0.z = __expf(v0.z - mx); v0.w = __expf(v0.w - mx);
    v1.x = __expf(v1.x - mx); v1.y = __expf(v1.y - mx);
    v1.z = __expf(v1.z - mx); v1.w = __expf(v1.w - mx);

    float s = v0.x + v0.y + v0.z + v0.w + v1.x + v1.y + v1.z + v1.w;
#pragma unroll
    for (int off = 32; off > 0; off >>= 1) s += __shfl_down(s, off);
    if (lane == 0) red[wav] = s;
    __syncthreads();
    s = red[0] + red[1] + red[2] + red[3];
    float inv = 1.0f / s;

    ushort4 o0, o1;
    o0.x = f2bf(v0.x * inv); o0.y = f2bf(v0.y * inv);
    o0.z = f2bf(v0.z * inv); o0.w = f2bf(v0.w * inv);
    o1.x = f2bf(v1.x * inv); o1.y = f2bf(v1.y * inv);
    o1.z = f2bf(v1.z * inv); o1.w = f2bf(v1.w * inv);
    *(ushort4*)(pr + tid * 4)        = o0;
    *(ushort4*)(pr + 1024 + tid * 4) = o1;
}

// ---------------------------------------------------------------------------
// out_row = LayerNorm(x_row + y_row)*g + b.  D = 1024. Optional bf16 copy.
// Safe when out == y.
// ---------------------------------------------------------------------------
template<int WRITE_BF16>
__global__ __launch_bounds__(256) void add_ln_kernel(
    const float* __restrict__ X, const float* __restrict__ Y,
    const float* __restrict__ g, const float* __restrict__ bta,
    float* __restrict__ out, unsigned short* __restrict__ out16, int D)
{
    __shared__ float red[8];
    const int row = blockIdx.x;
    const float* x = X + (size_t)row * D;
    const float* y = Y + (size_t)row * D;
    const int tid  = threadIdx.x;
    const int lane = tid & 63;
    const int wav  = tid >> 6;

    float4 a  = *(const float4*)(x + tid * 4);
    float4 b4 = *(const float4*)(y + tid * 4);
    float v0 = a.x + b4.x, v1 = a.y + b4.y, v2 = a.z + b4.z, v3 = a.w + b4.w;

    float s1 = v0 + v1 + v2 + v3;
    float s2 = v0 * v0 + v1 * v1 + v2 * v2 + v3 * v3;
#pragma unroll
    for (int off = 32; off > 0; off >>= 1) {
        s1 += __shfl_down(s1, off);
        s2 += __shfl_down(s2, off);
    }
    if (lane == 0) { red[wav] = s1; red[4 + wav] = s2; }
    __syncthreads();
    s1 = red[0] + red[1] + red[2] + red[3];
    s2 = red[4] + red[5] + red[6] + red[7];
    const float mu  = s1 / (float)D;
    const float var = s2 / (float)D - mu * mu;
    const float rs  = rsqrtf(var + LN_EPS);

    float4 gg = *(const float4*)(g + tid * 4);
    float4 bb = *(const float4*)(bta + tid * 4);
    float4 r;
    r.x = (v0 - mu) * rs * gg.x + bb.x;
    r.y = (v1 - mu) * rs * gg.y + bb.y;
    r.z = (v2 - mu) * rs * gg.z + bb.z;
    r.w = (v3 - mu) * rs * gg.w + bb.w;
    *(float4*)(out + (size_t)row * D + tid * 4) = r;
    if (WRITE_BF16) {
        ushort4 h;
        h.x = f2bf(r.x); h.y = f2bf(r.y); h.z = f2bf(r.z); h.w = f2bf(r.w);
        *(ushort4*)(out16 + (size_t)row * D + tid * 4) = h;
    }
}

// ---------------------------------------------------------------------------
extern "C" void kernel_launch(void* const* d_in, const int* in_sizes, int n_in,
                              void* d_out, int out_size, void* d_ws, size_t ws_size,
                              hipStream_t stream) {
    (void)in_sizes; (void)n_in; (void)out_size; (void)ws_size;
    const float* x    = (const float*)d_in[0];
    const float* mask = (const float*)d_in[1];
    const float* w1   = (const float*)d_in[2];
    const float* b1   = (const float*)d_in[3];
    const float* w2   = (const float*)d_in[4];
    const float* b2   = (const float*)d_in[5];
    const float* ln1g = (const float*)d_in[6];
    const float* ln1b = (const float*)d_in[7];
    const float* ln2g = (const float*)d_in[8];
    const float* ln2b = (const float*)d_in[9];
    float* out = (float*)d_out;

    const int B = 4, S = 2048, D = 1024, DFF = 4096;

    // ws regions (128 MB total, sequential reuse):
    //  [0,64M):  scores fp32 (steps 1-2)  -> act bf16 (steps 5-6)
    //  [64M,96M): xb bf16 (prep-1) -> probs bf16 (2-3) -> hb16 (4-5) -> ffn fp32 (6-7)
    //  [96M,128M): hbuf fp32 (3-7)
    // d_out (32 MB) as scratch until step 7: xTb [0,16M), w1T [16,24M), w2T [24,32M)
    char* ws = (char*)d_ws;
    float*          scores = (float*)ws;
    unsigned short* act    = (unsigned short*)ws;
    char* r1 = ws + (size_t)64 * 1024 * 1024;
    unsigned short* xb    = (unsigned short*)r1;
    unsigned short* probs = (unsigned short*)r1;
    unsigned short* hb16  = (unsigned short*)r1;
    float*          ffn   = (float*)r1;
    float* hbuf = (float*)(ws + (size_t)96 * 1024 * 1024);
    unsigned short* xTb = (unsigned short*)d_out;
    unsigned short* w1T = (unsigned short*)((char*)d_out + (size_t)16 * 1024 * 1024);
    unsigned short* w2T = (unsigned short*)((char*)d_out + (size_t)24 * 1024 * 1024);

    // --- prep: bf16 casts / transposes ---
    cvt_bf16_kernel<<<(B * S * D) / 1024, 256, 0, stream>>>(x, xb);
    transpose_cvt_kernel<<<dim3(D / 32, S / 32, B), 256, 0, stream>>>(
        x, xTb, S, D, (long)S * D, (long)S * D);
    transpose_cvt_kernel<<<dim3(DFF / 32, D / 32, 1), 256, 0, stream>>>(
        w1, w1T, D, DFF, 0L, 0L);
    transpose_cvt_kernel<<<dim3(D / 32, DFF / 32, 1), 256, 0, stream>>>(
        w2, w2T, DFF, D, 0L, 0L);

    // 1. scores[b] = xb[b] @ xb[b]^T          (M=N=S, K=D)
    hipLaunchKernelGGL((gemm_bt<0>), dim3(S / 128, S / 128, B), dim3(256), 0, stream,
                       xb, xb, (const float*)nullptr, (void*)scores,
                       S, S, D, (long)S * D, (long)S * D, (long)S * S);
    // 2. probs = softmax(scores*scale + mask) -> bf16
    softmax_kernel<<<B * S, 256, 0, stream>>>(scores, probs, mask, S, 0.03125f);
    // 3. attn[b] = probs[b] @ xTb[b]^T        (M=S, N=D, K=S)
    hipLaunchKernelGGL((gemm_bt<0>), dim3(D / 128, S / 128, B), dim3(256), 0, stream,
                       probs, xTb, (const float*)nullptr, (void*)hbuf,
                       S, D, S, (long)S * S, (long)D * S, (long)S * D);
    // 4. h = LN(x + attn) -> hbuf fp32 (in place) + hb16 bf16
    hipLaunchKernelGGL((add_ln_kernel<1>), dim3(B * S), dim3(256), 0, stream,
                       x, hbuf, ln1g, ln1b, hbuf, hb16, D);
    // 5. act = gelu(h @ w1 + b1) -> bf16      (M=B*S, N=DFF, K=D)
    hipLaunchKernelGGL((gemm_bt<2>), dim3(DFF / 128, (B * S) / 128, 1), dim3(256), 0, stream,
                       hb16, w1T, b1, (void*)act,
                       B * S, DFF, D, 0L, 0L, 0L);
    // 6. ffn = act @ w2 + b2 -> fp32          (M=B*S, N=D, K=DFF)
    hipLaunchKernelGGL((gemm_bt<1>), dim3(D / 128, (B * S) / 128, 1), dim3(256), 0, stream,
                       act, w2T, b2, (void*)ffn,
                       B * S, D, DFF, 0L, 0L, 0L);
    // 7. out = LN(h + ffn)
    hipLaunchKernelGGL((add_ln_kernel<0>), dim3(B * S), dim3(256), 0, stream,
                       hbuf, ffn, ln2g, ln2b, out, (unsigned short*)nullptr, D);
}

// Round 3
// 473.145 us; speedup vs baseline: 2.2518x; 1.1221x over previous
//
#include <hip/hip_runtime.h>
#include <hip/hip_bf16.h>
#include <math.h>

#define LN_EPS 1e-5f

typedef short short8 __attribute__((ext_vector_type(8)));
typedef float floatx4 __attribute__((ext_vector_type(4)));

__device__ inline unsigned short f2bf(float f) {
    unsigned int u = __float_as_uint(f);
    u += 0x7fff + ((u >> 16) & 1);   // round-to-nearest-even
    return (unsigned short)(u >> 16);
}

__device__ inline void gl_lds16(const unsigned short* g, unsigned short* l) {
    __builtin_amdgcn_global_load_lds(
        (__attribute__((address_space(1))) const void*)g,
        (__attribute__((address_space(3))) void*)l, 16, 0, 0);
}

// overflow-safe tanh-approx GELU (max abs err ~1e-3 vs exact)
__device__ inline float gelu_f(float v) {
    float u2 = 2.0f * v * (0.7978845608f + 0.0356774081f * v * v);
    float t  = 1.0f - 2.0f / (__expf(u2) + 1.0f);
    return 0.5f * v * (1.0f + t);
}

// ---------------------------------------------------------------------------
// bf16 MFMA GEMM, 128x128 tile, 64-K per barrier interval (2x [128][32] LDS).
//  A: MxK row-major bf16.   B: NxK row-major bf16 (B^T given).
//  EPI: 0 = fp32 store; 1 = +bias fp32; 2 = +bias, GELU, bf16;
//       3 = *scale + maskrow[col] (per-batch), bf16   (QK^T scores)
// M,N mult of 128; K mult of 64.
// ---------------------------------------------------------------------------
template<int EPI>
__global__ __launch_bounds__(256) void gemm_bt(
    const unsigned short* __restrict__ A, const unsigned short* __restrict__ B,
    const float* __restrict__ bias, void* __restrict__ Cptr,
    int M, int N, int K, long sA, long sB, long sC, long sBias, float scale)
{
    __shared__ unsigned short lds_a[2 * 128 * 32];   // two k-half tiles [m][k]
    __shared__ unsigned short lds_b[2 * 128 * 32];

    const int tid  = threadIdx.x;
    const int lane = tid & 63;
    const int wave = tid >> 6;
    const int quad = lane >> 4;
    const int l16  = lane & 15;
    const int wm = wave >> 1, wn = wave & 1;
    const int tile_m = blockIdx.y * 128;
    const int tile_n = blockIdx.x * 128;
    const int batch  = blockIdx.z;

    const unsigned short* Ab = A + (size_t)batch * sA;
    const unsigned short* Bb = B + (size_t)batch * sB;

    const int srow = wave * 16 + (lane >> 2);
    const int scol = (lane & 3) * 8;
    const unsigned short* gA0 = Ab + (size_t)(tile_m + srow) * K + scol;
    const unsigned short* gA1 = Ab + (size_t)(tile_m + 64 + srow) * K + scol;
    const unsigned short* gB0 = Bb + (size_t)(tile_n + srow) * K + scol;
    const unsigned short* gB1 = Bb + (size_t)(tile_n + 64 + srow) * K + scol;
    unsigned short* lA0 = &lds_a[wave * 512 + lane * 8];
    unsigned short* lA1 = &lds_a[2048 + wave * 512 + lane * 8];
    unsigned short* lB0 = &lds_b[wave * 512 + lane * 8];
    unsigned short* lB1 = &lds_b[2048 + wave * 512 + lane * 8];

    floatx4 acc[4][4];
    const floatx4 zero = {0.f, 0.f, 0.f, 0.f};
#pragma unroll
    for (int i = 0; i < 4; i++)
#pragma unroll
        for (int j = 0; j < 4; j++) acc[i][j] = zero;

    for (int k0 = 0; k0 < K; k0 += 64) {
        __syncthreads();
        gl_lds16(gA0 + k0, lA0);
        gl_lds16(gA1 + k0, lA1);
        gl_lds16(gB0 + k0, lB0);
        gl_lds16(gB1 + k0, lB1);
        gl_lds16(gA0 + k0 + 32, lA0 + 4096);
        gl_lds16(gA1 + k0 + 32, lA1 + 4096);
        gl_lds16(gB0 + k0 + 32, lB0 + 4096);
        gl_lds16(gB1 + k0 + 32, lB1 + 4096);
        __syncthreads();

#pragma unroll
        for (int h = 0; h < 2; h++) {
            short8 afr[4], bfr[4];
#pragma unroll
            for (int i = 0; i < 4; i++)
                afr[i] = *(const short8*)
                    &lds_a[h * 4096 + (wm * 64 + i * 16 + l16) * 32 + quad * 8];
#pragma unroll
            for (int j = 0; j < 4; j++)
                bfr[j] = *(const short8*)
                    &lds_b[h * 4096 + (wn * 64 + j * 16 + l16) * 32 + quad * 8];
#pragma unroll
            for (int i = 0; i < 4; i++)
#pragma unroll
                for (int j = 0; j < 4; j++)
                    acc[i][j] = __builtin_amdgcn_mfma_f32_16x16x32_bf16(
                        afr[i], bfr[j], acc[i][j], 0, 0, 0);
        }
    }

    // ---- epilogue ----
#pragma unroll
    for (int i = 0; i < 4; i++) {
#pragma unroll
        for (int j = 0; j < 4; j++) {
            int col = tile_n + wn * 64 + j * 16 + l16;
            float addv = 0.f;
            if (EPI == 1 || EPI == 2) addv = bias[col];
            if (EPI == 3) addv = bias[(size_t)batch * sBias + col];
#pragma unroll
            for (int r = 0; r < 4; r++) {
                int row = tile_m + wm * 64 + i * 16 + quad * 4 + r;
                float v = acc[i][j][r];
                if (EPI == 3) v = v * scale + addv;
                else if (EPI >= 1) v += addv;
                if (EPI == 2) v = gelu_f(v);
                if (EPI == 2 || EPI == 3) {
                    unsigned short* C = (unsigned short*)Cptr + (size_t)batch * sC;
                    C[(size_t)row * N + col] = f2bf(v);
                } else {
                    float* C = (float*)Cptr + (size_t)batch * sC;
                    C[(size_t)row * N + col] = v;
                }
            }
        }
    }
}

// ---------------------------------------------------------------------------
__global__ __launch_bounds__(256) void cvt_bf16_kernel(
    const float* __restrict__ in, unsigned short* __restrict__ out)
{
    size_t i = ((size_t)blockIdx.x * 256 + threadIdx.x) * 4;
    float4 v = *(const float4*)(in + i);
    ushort4 h;
    h.x = f2bf(v.x); h.y = f2bf(v.y); h.z = f2bf(v.z); h.w = f2bf(v.w);
    *(ushort4*)(out + i) = h;
}

// ---------------------------------------------------------------------------
__global__ __launch_bounds__(256) void transpose_cvt_kernel(
    const float* __restrict__ in, unsigned short* __restrict__ out,
    int R, int C, long sIn, long sOut)
{
    __shared__ float tile[32][33];
    const int tc = blockIdx.x * 32, tr = blockIdx.y * 32;
    const float* src = in + (size_t)blockIdx.z * sIn;
    unsigned short* dst = out + (size_t)blockIdx.z * sOut;
    const int tx = threadIdx.x & 31, ty = threadIdx.x >> 5;
#pragma unroll
    for (int i = 0; i < 4; i++)
        tile[ty + i * 8][tx] = src[(size_t)(tr + ty + i * 8) * C + tc + tx];
    __syncthreads();
#pragma unroll
    for (int i = 0; i < 4; i++)
        dst[(size_t)(tc + ty + i * 8) * R + tr + tx] = f2bf(tile[tx][ty + i * 8]);
}

// ---------------------------------------------------------------------------
// Pure row softmax over S=2048: bf16 in (scale+mask pre-applied) -> bf16 out.
// ---------------------------------------------------------------------------
__global__ __launch_bounds__(256) void softmax_bf16_kernel(
    const unsigned short* __restrict__ scores, unsigned short* __restrict__ probs,
    int S)
{
    __shared__ float red[4];
    const int row = blockIdx.x;
    const unsigned short* p = scores + (size_t)row * S;
    unsigned short* pr      = probs  + (size_t)row * S;
    const int tid  = threadIdx.x;
    const int lane = tid & 63;
    const int wav  = tid >> 6;

    uint4 raw = *(const uint4*)(p + tid * 8);   // 8 bf16
    float v[8];
    v[0] = __uint_as_float(raw.x << 16); v[1] = __uint_as_float(raw.x & 0xffff0000u);
    v[2] = __uint_as_float(raw.y << 16); v[3] = __uint_as_float(raw.y & 0xffff0000u);
    v[4] = __uint_as_float(raw.z << 16); v[5] = __uint_as_float(raw.z & 0xffff0000u);
    v[6] = __uint_as_float(raw.w << 16); v[7] = __uint_as_float(raw.w & 0xffff0000u);

    float mx = v[0];
#pragma unroll
    for (int k = 1; k < 8; k++) mx = fmaxf(mx, v[k]);
#pragma unroll
    for (int off = 32; off > 0; off >>= 1) mx = fmaxf(mx, __shfl_down(mx, off));
    if (lane == 0) red[wav] = mx;
    __syncthreads();
    mx = fmaxf(fmaxf(red[0], red[1]), fmaxf(red[2], red[3]));
    __syncthreads();

    float s = 0.f;
#pragma unroll
    for (int k = 0; k < 8; k++) { v[k] = __expf(v[k] - mx); s += v[k]; }
#pragma unroll
    for (int off = 32; off > 0; off >>= 1) s += __shfl_down(s, off);
    if (lane == 0) red[wav] = s;
    __syncthreads();
    s = red[0] + red[1] + red[2] + red[3];
    float inv = 1.0f / s;

    uint4 o;
    o.x = (unsigned)f2bf(v[0] * inv) | ((unsigned)f2bf(v[1] * inv) << 16);
    o.y = (unsigned)f2bf(v[2] * inv) | ((unsigned)f2bf(v[3] * inv) << 16);
    o.z = (unsigned)f2bf(v[4] * inv) | ((unsigned)f2bf(v[5] * inv) << 16);
    o.w = (unsigned)f2bf(v[6] * inv) | ((unsigned)f2bf(v[7] * inv) << 16);
    *(uint4*)(pr + tid * 8) = o;
}

// ---------------------------------------------------------------------------
template<int WRITE_BF16>
__global__ __launch_bounds__(256) void add_ln_kernel(
    const float* __restrict__ X, const float* __restrict__ Y,
    const float* __restrict__ g, const float* __restrict__ bta,
    float* __restrict__ out, unsigned short* __restrict__ out16, int D)
{
    __shared__ float red[8];
    const int row = blockIdx.x;
    const float* x = X + (size_t)row * D;
    const float* y = Y + (size_t)row * D;
    const int tid  = threadIdx.x;
    const int lane = tid & 63;
    const int wav  = tid >> 6;

    float4 a  = *(const float4*)(x + tid * 4);
    float4 b4 = *(const float4*)(y + tid * 4);
    float v0 = a.x + b4.x, v1 = a.y + b4.y, v2 = a.z + b4.z, v3 = a.w + b4.w;

    float s1 = v0 + v1 + v2 + v3;
    float s2 = v0 * v0 + v1 * v1 + v2 * v2 + v3 * v3;
#pragma unroll
    for (int off = 32; off > 0; off >>= 1) {
        s1 += __shfl_down(s1, off);
        s2 += __shfl_down(s2, off);
    }
    if (lane == 0) { red[wav] = s1; red[4 + wav] = s2; }
    __syncthreads();
    s1 = red[0] + red[1] + red[2] + red[3];
    s2 = red[4] + red[5] + red[6] + red[7];
    const float mu  = s1 / (float)D;
    const float var = s2 / (float)D - mu * mu;
    const float rs  = rsqrtf(var + LN_EPS);

    float4 gg = *(const float4*)(g + tid * 4);
    float4 bb = *(const float4*)(bta + tid * 4);
    float4 r;
    r.x = (v0 - mu) * rs * gg.x + bb.x;
    r.y = (v1 - mu) * rs * gg.y + bb.y;
    r.z = (v2 - mu) * rs * gg.z + bb.z;
    r.w = (v3 - mu) * rs * gg.w + bb.w;
    *(float4*)(out + (size_t)row * D + tid * 4) = r;
    if (WRITE_BF16) {
        ushort4 h;
        h.x = f2bf(r.x); h.y = f2bf(r.y); h.z = f2bf(r.z); h.w = f2bf(r.w);
        *(ushort4*)(out16 + (size_t)row * D + tid * 4) = h;
    }
}

// ---------------------------------------------------------------------------
extern "C" void kernel_launch(void* const* d_in, const int* in_sizes, int n_in,
                              void* d_out, int out_size, void* d_ws, size_t ws_size,
                              hipStream_t stream) {
    (void)in_sizes; (void)n_in; (void)out_size; (void)ws_size;
    const float* x    = (const float*)d_in[0];
    const float* mask = (const float*)d_in[1];
    const float* w1   = (const float*)d_in[2];
    const float* b1   = (const float*)d_in[3];
    const float* w2   = (const float*)d_in[4];
    const float* b2   = (const float*)d_in[5];
    const float* ln1g = (const float*)d_in[6];
    const float* ln1b = (const float*)d_in[7];
    const float* ln2g = (const float*)d_in[8];
    const float* ln2b = (const float*)d_in[9];
    float* out = (float*)d_out;

    const int B = 4, S = 2048, D = 1024, DFF = 4096;

    // ws regions (128 MB, sequential reuse):
    //  [0,64M):   scoresb bf16 (1-2) -> act bf16 (5-6)
    //  [64M,96M): xb bf16 (prep-1) -> probs bf16 (2-3) -> hb16 (4-5) -> ffn fp32 (6-7)
    //  [96M,128M): hbuf fp32 (3-7)
    // d_out scratch until step 7: xTb [0,16M), w1T [16,24M), w2T [24,32M)
    char* ws = (char*)d_ws;
    unsigned short* scoresb = (unsigned short*)ws;
    unsigned short* act     = (unsigned short*)ws;
    char* r1 = ws + (size_t)64 * 1024 * 1024;
    unsigned short* xb    = (unsigned short*)r1;
    unsigned short* probs = (unsigned short*)r1;
    unsigned short* hb16  = (unsigned short*)r1;
    float*          ffn   = (float*)r1;
    float* hbuf = (float*)(ws + (size_t)96 * 1024 * 1024);
    unsigned short* xTb = (unsigned short*)d_out;
    unsigned short* w1T = (unsigned short*)((char*)d_out + (size_t)16 * 1024 * 1024);
    unsigned short* w2T = (unsigned short*)((char*)d_out + (size_t)24 * 1024 * 1024);

    // --- prep ---
    cvt_bf16_kernel<<<(B * S * D) / 1024, 256, 0, stream>>>(x, xb);
    transpose_cvt_kernel<<<dim3(D / 32, S / 32, B), 256, 0, stream>>>(
        x, xTb, S, D, (long)S * D, (long)S * D);
    transpose_cvt_kernel<<<dim3(DFF / 32, D / 32, 1), 256, 0, stream>>>(
        w1, w1T, D, DFF, 0L, 0L);
    transpose_cvt_kernel<<<dim3(D / 32, DFF / 32, 1), 256, 0, stream>>>(
        w2, w2T, DFF, D, 0L, 0L);

    // 1. scoresb[b] = (xb[b] @ xb[b]^T)*scale + mask  -> bf16
    hipLaunchKernelGGL((gemm_bt<3>), dim3(S / 128, S / 128, B), dim3(256), 0, stream,
                       xb, xb, mask, (void*)scoresb,
                       S, S, D, (long)S * D, (long)S * D, (long)S * S, (long)S, 0.03125f);
    // 2. probs = softmax(scoresb) -> bf16
    softmax_bf16_kernel<<<B * S, 256, 0, stream>>>(scoresb, probs, S);
    // 3. attn[b] = probs[b] @ xTb[b]^T -> fp32
    hipLaunchKernelGGL((gemm_bt<0>), dim3(D / 128, S / 128, B), dim3(256), 0, stream,
                       probs, xTb, (const float*)nullptr, (void*)hbuf,
                       S, D, S, (long)S * S, (long)D * S, (long)S * D, 0L, 0.f);
    // 4. h = LN(x + attn) -> hbuf fp32 + hb16 bf16
    hipLaunchKernelGGL((add_ln_kernel<1>), dim3(B * S), dim3(256), 0, stream,
                       x, hbuf, ln1g, ln1b, hbuf, hb16, D);
    // 5. act = gelu(h @ w1 + b1) -> bf16
    hipLaunchKernelGGL((gemm_bt<2>), dim3(DFF / 128, (B * S) / 128, 1), dim3(256), 0, stream,
                       hb16, w1T, b1, (void*)act,
                       B * S, DFF, D, 0L, 0L, 0L, 0L, 0.f);
    // 6. ffn = act @ w2 + b2 -> fp32
    hipLaunchKernelGGL((gemm_bt<1>), dim3(D / 128, (B * S) / 128, 1), dim3(256), 0, stream,
                       act, w2T, b2, (void*)ffn,
                       B * S, D, DFF, 0L, 0L, 0L, 0L, 0.f);
    // 7. out = LN(h + ffn)
    hipLaunchKernelGGL((add_ln_kernel<0>), dim3(B * S), dim3(256), 0, stream,
                       hbuf, ffn, ln2g, ln2b, out, (unsigned short*)nullptr, D);
}